// Round 9
// baseline (196.595 us; speedup 1.0000x reference)
//
#include <hip/hip_runtime.h>
#include <math.h>

// Problem constants (fixed by the reference file)
#define B_    4
#define LQ_   4096
#define C_    384
#define NH_   6
#define NP_   4
#define HL_   64
#define WL_   64
#define LV_   (HL_ * WL_)          // 4096
#define ROWS_ (B_ * LQ_)           // 16384
#define EPS_  1e-6f
#define NOFF_ 48                   // NH*NL*NP*2
#define NLOG_ 24                   // NH*NL*NP
#define WCTR_ 80                   // WcT rows (48 offs + 24 logits + 8 zero-pad)

typedef unsigned short u16;
typedef unsigned int   u32;
typedef __bf16 bf16x8 __attribute__((ext_vector_type(8)));
typedef float  f32x4  __attribute__((ext_vector_type(4)));

__device__ __forceinline__ u16 f2bf(float f) {
    u32 u = __float_as_uint(f);
    u += 0x7fff + ((u >> 16) & 1);          // RTNE
    return (u16)(u >> 16);
}
__device__ __forceinline__ u32 pack2bf(float a, float b) {
    return (u32)f2bf(a) | ((u32)f2bf(b) << 16);
}

__device__ __forceinline__ f32x4 mfma16(bf16x8 a, bf16x8 b, f32x4 c) {
    return __builtin_amdgcn_mfma_f32_16x16x32_bf16(a, b, c, 0, 0, 0);
}

// ---------------------------------------------------------------------------
// Fused LayerNorm (blocks 0..8191, vectorized, 32 waves/CU) + weight prep.
// ---------------------------------------------------------------------------
#define LN_BLOCKS_   8192
#define PREP_BLOCKS_ 1273   // ceil((2*384*384 + 80*384 + 80)/256)

__global__ __launch_bounds__(256) void ln_prep(
    const float* __restrict__ query, const float* __restrict__ feat,
    const float* __restrict__ qg, const float* __restrict__ qbv,
    const float* __restrict__ fg, const float* __restrict__ fbv,
    u16* __restrict__ qout, u16* __restrict__ fout,
    const float* __restrict__ Wv, const float* __restrict__ Wout,
    const float* __restrict__ Wo, const float* __restrict__ Wa,
    const float* __restrict__ bo, const float* __restrict__ ba,
    u16* __restrict__ WvT, u16* __restrict__ WoutT, u16* __restrict__ WcT,
    float* __restrict__ bias_c)
{
    if (blockIdx.x < LN_BLOCKS_) {
        int wid  = threadIdx.x >> 6;
        int lane = threadIdx.x & 63;
        int row  = blockIdx.x * 4 + wid;          // 0 .. 32767
        const float *src, *g, *bsh;
        u16* dst;
        int r;
        if (row < ROWS_) { src = query; g = qg; bsh = qbv; dst = qout; r = row; }
        else             { src = feat;  g = fg; bsh = fbv; dst = fout; r = row - ROWS_; }

        const float* x = src + (size_t)r * C_;
        float4 a4 = *(const float4*)(x + 4 * lane);
        float2 a2 = *(const float2*)(x + 256 + 2 * lane);
        float v0 = a4.x, v1 = a4.y, v2 = a4.z, v3 = a4.w, v4 = a2.x, v5 = a2.y;

        float s = v0 + v1 + v2 + v3 + v4 + v5;
#pragma unroll
        for (int off = 32; off; off >>= 1) s += __shfl_xor(s, off);
        float mu = s * (1.f / C_);

        float d0 = v0 - mu, d1 = v1 - mu, d2 = v2 - mu;
        float d3 = v3 - mu, d4 = v4 - mu, d5 = v5 - mu;
        float s2 = d0*d0 + d1*d1 + d2*d2 + d3*d3 + d4*d4 + d5*d5;
#pragma unroll
        for (int off = 32; off; off >>= 1) s2 += __shfl_xor(s2, off);
        float rs = rsqrtf(s2 * (1.f / C_) + EPS_);

        float4 g4 = *(const float4*)(g + 4 * lane);
        float4 b4 = *(const float4*)(bsh + 4 * lane);
        float2 g2 = *(const float2*)(g + 256 + 2 * lane);
        float2 b2 = *(const float2*)(bsh + 256 + 2 * lane);

        float o0 = d0 * rs * g4.x + b4.x;
        float o1 = d1 * rs * g4.y + b4.y;
        float o2 = d2 * rs * g4.z + b4.z;
        float o3 = d3 * rs * g4.w + b4.w;
        float o4 = d4 * rs * g2.x + b2.x;
        float o5 = d5 * rs * g2.y + b2.y;

        u16* y = dst + (size_t)r * C_;
        uint2 w0; w0.x = pack2bf(o0, o1); w0.y = pack2bf(o2, o3);
        *(uint2*)(y + 4 * lane) = w0;
        *(u32*)(y + 256 + 2 * lane) = pack2bf(o4, o5);
    } else {
        const int KN = 384 * 384;
        int idx = (blockIdx.x - LN_BLOCKS_) * 256 + threadIdx.x;
        if (idx < KN) {
            int n = idx / 384, k = idx - n * 384;
            WvT[idx] = f2bf(Wv[k * 384 + n]);
        } else if (idx < 2 * KN) {
            int t = idx - KN;
            int n = t / 384, k = t - n * 384;
            WoutT[t] = f2bf(Wout[k * 384 + n]);
        } else if (idx < 2 * KN + WCTR_ * 384) {
            int t = idx - 2 * KN;
            int n = t / 384, k = t - n * 384;
            float v = (n < 48) ? Wo[k * 48 + n] : (n < 72 ? Wa[k * 24 + (n - 48)] : 0.f);
            WcT[t] = f2bf(v);
        } else if (idx < 2 * KN + WCTR_ * 384 + 80) {
            int n = idx - (2 * KN + WCTR_ * 384);
            bias_c[n] = (n < 48) ? bo[n] : (n < 72 ? ba[n - 48] : 0.f);
        }
    }
}

// ---------------------------------------------------------------------------
// Combined GEMM dispatch — LDS-FREE, BARRIER-FREE direct-MFMA.
// Rationale (R0/R1/R4/R6 series + R3 PMC): every LDS-staged variant is
// synchronization/latency-bound (MfmaUtil 3.9%, all pipes idle) and none
// breaks ~162 us total. K=384 is tiny and L2-resident: each lane loads its
// MFMA fragments straight global->VGPR (16 B/lane; 4 quads of one fr make a
// contiguous 64 B segment; A elements read exactly once per block, B from
// L2). 2-deep register prefetch, fully unrolled 12-step K-loop, ZERO
// barriers, ZERO LDS -> occupancy is VGPR-limited (~12-16 waves/CU) and
// stalls are covered by independent waves (TLP), exactly like the sampler.
// Fragment address algebra identical to the old LDS reads -> same
// accumulation order -> same absmax.
//   blocks 0..383:  value path, 128x128 tile (waves 2x2, 64x64/wave)
//     XCD-affinity swizzle: m = g&127, n = g>>7.
//   blocks 384..511: small path, 128x80 tile (waves 4x1, 32x80/wave)
// ---------------------------------------------------------------------------
__global__ __launch_bounds__(256) void gemm_combined(
    const u16* __restrict__ fb, const u16* __restrict__ qb,
    const u16* __restrict__ WvT, const u16* __restrict__ WcT,
    const float* __restrict__ bv, const float* __restrict__ bias_c,
    u16* __restrict__ valb, float* __restrict__ offs, float* __restrict__ logits)
{
    int g    = blockIdx.x;
    int tid  = threadIdx.x;
    int lane = tid & 63, wid = tid >> 6;
    int fr = lane & 15, quad = lane >> 4;

    if (g < 384) {
        // ---------------- value path: 128x128 ----------------
        int m0 = (g & 127) * 128, n0 = (g >> 7) * 128;   // XCD-affinity swizzle
        int wm = (wid >> 1) * 64, wn = (wid & 1) * 64;
        const u16* aBase = fb  + (size_t)(m0 + wm + fr) * 384 + quad * 8;
        const u16* bBase = WvT + (size_t)(n0 + wn + fr) * 384 + quad * 8;

        f32x4 zero = {0.f, 0.f, 0.f, 0.f};
        f32x4 acc[4][4];
#pragma unroll
        for (int i = 0; i < 4; ++i)
#pragma unroll
            for (int j = 0; j < 4; ++j) acc[i][j] = zero;

        bf16x8 af[2][4], bf[2][4];
#pragma unroll
        for (int i = 0; i < 4; ++i) {
            af[0][i] = *(const bf16x8*)(aBase + (size_t)i * 16 * 384);
            bf[0][i] = *(const bf16x8*)(bBase + (size_t)i * 16 * 384);
        }
#pragma unroll
        for (int t = 0; t < 12; ++t) {
            const int cur = t & 1, nxt = cur ^ 1;
            if (t < 11) {
#pragma unroll
                for (int i = 0; i < 4; ++i) {
                    af[nxt][i] = *(const bf16x8*)(aBase + (size_t)i * 16 * 384 + (t + 1) * 32);
                    bf[nxt][i] = *(const bf16x8*)(bBase + (size_t)i * 16 * 384 + (t + 1) * 32);
                }
            }
#pragma unroll
            for (int i = 0; i < 4; ++i)
#pragma unroll
                for (int j = 0; j < 4; ++j)
                    acc[i][j] = mfma16(af[cur][i], bf[cur][j], acc[i][j]);
        }

#pragma unroll
        for (int i = 0; i < 4; ++i) {
            int row = m0 + wm + i * 16 + quad * 4;
#pragma unroll
            for (int j = 0; j < 4; ++j) {
                int col = n0 + wn + j * 16 + fr;
                float bcol = bv[col];
#pragma unroll
                for (int r = 0; r < 4; ++r)
                    valb[(size_t)(row + r) * C_ + col] = f2bf(acc[i][j][r] + bcol);
            }
        }
    } else {
        // ---------------- small path: 128x80 ----------------
        int m0 = (g - 384) * 128;
        int wm = wid * 32;
        const u16* aBase = qb  + (size_t)(m0 + wm + fr) * 384 + quad * 8;
        const u16* bBase = WcT + (size_t)fr * 384 + quad * 8;

        f32x4 zero = {0.f, 0.f, 0.f, 0.f};
        f32x4 acc[2][5];
#pragma unroll
        for (int i = 0; i < 2; ++i)
#pragma unroll
            for (int j = 0; j < 5; ++j) acc[i][j] = zero;

        bf16x8 af[2][2], bf[2][5];
#pragma unroll
        for (int i = 0; i < 2; ++i)
            af[0][i] = *(const bf16x8*)(aBase + (size_t)i * 16 * 384);
#pragma unroll
        for (int j = 0; j < 5; ++j)
            bf[0][j] = *(const bf16x8*)(bBase + (size_t)j * 16 * 384);
#pragma unroll
        for (int t = 0; t < 12; ++t) {
            const int cur = t & 1, nxt = cur ^ 1;
            if (t < 11) {
#pragma unroll
                for (int i = 0; i < 2; ++i)
                    af[nxt][i] = *(const bf16x8*)(aBase + (size_t)i * 16 * 384 + (t + 1) * 32);
#pragma unroll
                for (int j = 0; j < 5; ++j)
                    bf[nxt][j] = *(const bf16x8*)(bBase + (size_t)j * 16 * 384 + (t + 1) * 32);
            }
#pragma unroll
            for (int i = 0; i < 2; ++i)
#pragma unroll
                for (int j = 0; j < 5; ++j)
                    acc[i][j] = mfma16(af[cur][i], bf[cur][j], acc[i][j]);
        }

#pragma unroll
        for (int i = 0; i < 2; ++i) {
            int row = m0 + wm + i * 16 + quad * 4;
#pragma unroll
            for (int j = 0; j < 5; ++j) {
                int col = j * 16 + fr;
                if (col < 72) {
                    float bcol = bias_c[col];
#pragma unroll
                    for (int r = 0; r < 4; ++r) {
                        float v = acc[i][j][r] + bcol;
                        if (col < 48) offs[(size_t)(row + r) * NOFF_ + col] = v;
                        else          logits[(size_t)(row + r) * NLOG_ + (col - 48)] = v;
                    }
                }
            }
        }
    }
}

// ---------------------------------------------------------------------------
// Standalone sampler: NO LDS, NO barriers. One thread = one (q, d-chunk):
// softmax+coords in registers, 16 bf16x8 gathers, one 16B coalesced store.
// 384 threads = 8 queries/block; 2048 blocks; XCD swizzle keeps one batch's
// value (3.1 MB) per XCD-pair L2.
// ---------------------------------------------------------------------------
__global__ __launch_bounds__(384) void sampler(
    const u16*  __restrict__ value,    // [B*LV, 384] bf16
    const float* __restrict__ rp,      // [B*LQ, 2]
    const float* __restrict__ offs,    // [B*LQ, 48]
    const float* __restrict__ logits,  // [B*LQ, 24]
    u16* __restrict__ attn)            // [B*LQ, 384] bf16
{
    int t = threadIdx.x;
    int g = blockIdx.x;
    int b     = (g & 7) >> 1;                        // batch -> XCD pair
    int local = ((g >> 3) << 1) | (g & 1);           // 0..511 within batch
    int q  = t / 48, dc = t - q * 48;
    int h  = dc >> 3;
    int col0 = dc << 3;                              // 0,8,...,376
    int r  = b * LQ_ + local * 8 + q;

    float4 lg  = *(const float4*)(logits + (size_t)r * NLOG_ + h * 4);
    float2 rpv = *(const float2*)(rp + (size_t)r * 2);
    float4 of0 = *(const float4*)(offs + (size_t)r * NOFF_ + h * 8);
    float4 of1 = *(const float4*)(offs + (size_t)r * NOFF_ + h * 8 + 4);

    float mx = fmaxf(fmaxf(lg.x, lg.y), fmaxf(lg.z, lg.w));
    float e0 = __expf(lg.x - mx), e1 = __expf(lg.y - mx);
    float e2 = __expf(lg.z - mx), e3 = __expf(lg.w - mx);
    float rden = 1.f / (e0 + e1 + e2 + e3);
    float aws[4] = {e0 * rden, e1 * rden, e2 * rden, e3 * rden};
    float oxs[4] = {of0.x, of0.z, of1.x, of1.z};
    float oys[4] = {of0.y, of0.w, of1.y, of1.w};

    const u16* vbase = value + (size_t)b * LV_ * C_ + col0;
    float acc[8] = {0.f, 0.f, 0.f, 0.f, 0.f, 0.f, 0.f, 0.f};
#pragma unroll
    for (int p = 0; p < NP_; ++p) {
        float x = rpv.x * (float)WL_ + oxs[p] - 0.5f;
        float y = rpv.y * (float)HL_ + oys[p] - 0.5f;
        float x0f = floorf(x), y0f = floorf(y);
        float wx = x - x0f, wy = y - y0f;
        int x0 = (int)x0f, y0 = (int)y0f;
#pragma unroll
        for (int c = 0; c < 4; ++c) {
            int xi = x0 + (c & 1);
            int yi = y0 + (c >> 1);
            bool valid = (xi >= 0) && (xi < WL_) && (yi >= 0) && (yi < HL_);
            int xc = xi < 0 ? 0 : (xi > WL_ - 1 ? WL_ - 1 : xi);
            int yc = yi < 0 ? 0 : (yi > HL_ - 1 ? HL_ - 1 : yi);
            float w = ((c & 1) ? wx : 1.f - wx) * ((c >> 1) ? wy : 1.f - wy) * aws[p];
            w = valid ? w : 0.f;
            bf16x8 vv = *(const bf16x8*)(vbase + (size_t)(yc * WL_ + xc) * C_);
#pragma unroll
            for (int e = 0; e < 8; ++e) acc[e] += w * (float)vv[e];
        }
    }

    uint4 o;
    o.x = pack2bf(acc[0], acc[1]);
    o.y = pack2bf(acc[2], acc[3]);
    o.z = pack2bf(acc[4], acc[5]);
    o.w = pack2bf(acc[6], acc[7]);
    *(uint4*)(attn + (size_t)r * C_ + col0) = o;
}

// ---------------------------------------------------------------------------
// Out GEMM: out = query + gamma * (attn @ WoutT^T + bout). 128x96 tile ->
// 512 blocks. LDS-FREE, BARRIER-FREE direct-MFMA (same rationale as
// gemm_combined). Waves 2x2, wave tile 64x48, acc[4][3].
// XCD-affinity: m = g&127, n = g>>7 (same-m blocks share an XCD for attn L2).
// ---------------------------------------------------------------------------
__global__ __launch_bounds__(256) void out_gemm(
    const u16* __restrict__ A, const u16* __restrict__ Bt,
    const float* __restrict__ bout, const float* __restrict__ gamma,
    const float* __restrict__ query, float* __restrict__ out)
{
    int g    = blockIdx.x;
    int tid  = threadIdx.x;
    int lane = tid & 63, wid = tid >> 6;
    int fr = lane & 15, quad = lane >> 4;

    int m0 = (g & 127) * 128, n0 = (g >> 7) * 96;
    int wm = (wid >> 1) * 64, wn = (wid & 1) * 48;
    const u16* aBase = A  + (size_t)(m0 + wm + fr) * 384 + quad * 8;
    const u16* bBase = Bt + (size_t)(n0 + wn + fr) * 384 + quad * 8;

    f32x4 zero = {0.f, 0.f, 0.f, 0.f};
    f32x4 acc[4][3];
#pragma unroll
    for (int i = 0; i < 4; ++i)
#pragma unroll
        for (int j = 0; j < 3; ++j) acc[i][j] = zero;

    bf16x8 af[2][4], bf[2][3];
#pragma unroll
    for (int i = 0; i < 4; ++i)
        af[0][i] = *(const bf16x8*)(aBase + (size_t)i * 16 * 384);
#pragma unroll
    for (int j = 0; j < 3; ++j)
        bf[0][j] = *(const bf16x8*)(bBase + (size_t)j * 16 * 384);
#pragma unroll
    for (int t = 0; t < 12; ++t) {
        const int cur = t & 1, nxt = cur ^ 1;
        if (t < 11) {
#pragma unroll
            for (int i = 0; i < 4; ++i)
                af[nxt][i] = *(const bf16x8*)(aBase + (size_t)i * 16 * 384 + (t + 1) * 32);
#pragma unroll
            for (int j = 0; j < 3; ++j)
                bf[nxt][j] = *(const bf16x8*)(bBase + (size_t)j * 16 * 384 + (t + 1) * 32);
        }
#pragma unroll
        for (int i = 0; i < 4; ++i)
#pragma unroll
            for (int j = 0; j < 3; ++j)
                acc[i][j] = mfma16(af[cur][i], bf[cur][j], acc[i][j]);
    }

#pragma unroll
    for (int i = 0; i < 4; ++i) {
        int row = m0 + wm + i * 16 + quad * 4;
#pragma unroll
        for (int j = 0; j < 3; ++j) {
            int col = n0 + wn + j * 16 + fr;
            float bc = bout[col], gm = gamma[col];
#pragma unroll
            for (int r = 0; r < 4; ++r) {
                size_t o = (size_t)(row + r) * C_ + col;
                out[o] = query[o] + gm * (acc[i][j][r] + bc);
            }
        }
    }
}

// ---------------------------------------------------------------------------
extern "C" void kernel_launch(void* const* d_in, const int* in_sizes, int n_in,
                              void* d_out, int out_size, void* d_ws, size_t ws_size,
                              hipStream_t stream)
{
    const float* query  = (const float*)d_in[0];
    const float* rp     = (const float*)d_in[1];
    const float* feat   = (const float*)d_in[2];
    const float* gamma  = (const float*)d_in[9];
    const float* Wv     = (const float*)d_in[10];
    const float* bv     = (const float*)d_in[11];
    const float* Wo     = (const float*)d_in[12];
    const float* bo     = (const float*)d_in[13];
    const float* Wa     = (const float*)d_in[14];
    const float* ba     = (const float*)d_in[15];
    const float* Wout   = (const float*)d_in[16];
    const float* bout   = (const float*)d_in[17];
    float* out = (float*)d_out;

    // Workspace layout
    u16* wsu    = (u16*)d_ws;
    u16* qb     = wsu;                                   // 16384*384
    u16* fb     = qb    + (size_t)ROWS_ * C_;
    u16* valb   = fb    + (size_t)ROWS_ * C_;
    u16* attnb  = valb  + (size_t)ROWS_ * C_;
    u16* WvT    = attnb + (size_t)ROWS_ * C_;            // 384*384
    u16* WoutT  = WvT   + 384 * 384;                     // 384*384
    u16* WcT    = WoutT + 384 * 384;                     // 80*384
    float* offs   = (float*)(WcT + WCTR_ * 384);         // 16384*48
    float* logits = offs + (size_t)ROWS_ * NOFF_;        // 16384*24
    float* bias_c = logits + (size_t)ROWS_ * NLOG_;      // 80

    // 1) LayerNorm (q,f -> bf16, vectorized, full occupancy) + weight prep
    ln_prep<<<LN_BLOCKS_ + PREP_BLOCKS_, 256, 0, stream>>>(
        query, feat,
        (const float*)d_in[5], (const float*)d_in[6],
        (const float*)d_in[7], (const float*)d_in[8],
        qb, fb, Wv, Wout, Wo, Wa, bo, ba, WvT, WoutT, WcT, bias_c);

    // 2) value GEMM 128x128 (384 blocks, XCD-affinity) + offs/logits GEMM —
    //    LDS-free, barrier-free, direct global->VGPR MFMA fragments
    gemm_combined<<<512, 256, 0, stream>>>(fb, qb, WvT, WcT, bv, bias_c,
                                           valb, offs, logits);

    // 3) sampler: barrier-free, register-only, coalesced bf16 attn out
    sampler<<<2048, 384, 0, stream>>>(valb, rp, offs, logits, attnb);

    // 4) out = query + gamma * (attn @ Wout + bout) — LDS-free direct MFMA
    out_gemm<<<512, 256, 0, stream>>>(attnb, WoutT, bout, gamma, query, out);
}

// Round 10
// 161.527 us; speedup vs baseline: 1.2171x; 1.2171x over previous
//
#include <hip/hip_runtime.h>
#include <math.h>

// Problem constants (fixed by the reference file)
#define B_    4
#define LQ_   4096
#define C_    384
#define NH_   6
#define NP_   4
#define HL_   64
#define WL_   64
#define LV_   (HL_ * WL_)          // 4096
#define ROWS_ (B_ * LQ_)           // 16384
#define EPS_  1e-6f
#define NOFF_ 48                   // NH*NL*NP*2
#define NLOG_ 24                   // NH*NL*NP
#define WCTR_ 96                   // WcT rows (80 used, padded for uniform staging)

typedef unsigned short u16;
typedef unsigned int   u32;
typedef __bf16 bf16x8 __attribute__((ext_vector_type(8)));
typedef float  f32x4  __attribute__((ext_vector_type(4)));

__device__ __forceinline__ u16 f2bf(float f) {
    u32 u = __float_as_uint(f);
    u += 0x7fff + ((u >> 16) & 1);          // RTNE
    return (u16)(u >> 16);
}
__device__ __forceinline__ u32 pack2bf(float a, float b) {
    return (u32)f2bf(a) | ((u32)f2bf(b) << 16);
}

__device__ __forceinline__ f32x4 mfma16(bf16x8 a, bf16x8 b, f32x4 c) {
    return __builtin_amdgcn_mfma_f32_16x16x32_bf16(a, b, c, 0, 0, 0);
}

// async global->LDS, 16 bytes per lane; LDS dst must be wave-uniform base + lane*16
__device__ __forceinline__ void gl_lds16(const u16* g, u16* l) {
    __builtin_amdgcn_global_load_lds(
        (const __attribute__((address_space(1))) unsigned int*)g,
        (__attribute__((address_space(3))) unsigned int*)l, 16, 0, 0);
}

// Counted waits + raw barrier (asm so no compiler-inserted vmcnt(0) drain,
// "memory" clobber so LDS reads can't cross them).
__device__ __forceinline__ void vm_wait8() { asm volatile("s_waitcnt vmcnt(8)" ::: "memory"); }
__device__ __forceinline__ void vm_wait7() { asm volatile("s_waitcnt vmcnt(7)" ::: "memory"); }
__device__ __forceinline__ void vm_wait0() { asm volatile("s_waitcnt vmcnt(0)" ::: "memory"); }
__device__ __forceinline__ void lgkm0()    { asm volatile("s_waitcnt lgkmcnt(0)" ::: "memory"); }
__device__ __forceinline__ void barrier_() { asm volatile("s_barrier" ::: "memory"); }

// ---------------------------------------------------------------------------
// Fused LayerNorm (blocks 0..8191, vectorized) + weight prep (rest).
// ---------------------------------------------------------------------------
#define LN_BLOCKS_   8192
#define PREP_BLOCKS_ 1297   // ceil((2*384*384 + 96*384 + 80)/256)

__global__ __launch_bounds__(256) void ln_prep(
    const float* __restrict__ query, const float* __restrict__ feat,
    const float* __restrict__ qg, const float* __restrict__ qbv,
    const float* __restrict__ fg, const float* __restrict__ fbv,
    u16* __restrict__ qout, u16* __restrict__ fout,
    const float* __restrict__ Wv, const float* __restrict__ Wout,
    const float* __restrict__ Wo, const float* __restrict__ Wa,
    const float* __restrict__ bo, const float* __restrict__ ba,
    u16* __restrict__ WvT, u16* __restrict__ WoutT, u16* __restrict__ WcT,
    float* __restrict__ bias_c)
{
    if (blockIdx.x < LN_BLOCKS_) {
        int wid  = threadIdx.x >> 6;
        int lane = threadIdx.x & 63;
        int row  = blockIdx.x * 4 + wid;          // 0 .. 32767
        const float *src, *g, *bsh;
        u16* dst;
        int r;
        if (row < ROWS_) { src = query; g = qg; bsh = qbv; dst = qout; r = row; }
        else             { src = feat;  g = fg; bsh = fbv; dst = fout; r = row - ROWS_; }

        const float* x = src + (size_t)r * C_;
        float4 a4 = *(const float4*)(x + 4 * lane);
        float2 a2 = *(const float2*)(x + 256 + 2 * lane);
        float v0 = a4.x, v1 = a4.y, v2 = a4.z, v3 = a4.w, v4 = a2.x, v5 = a2.y;

        float s = v0 + v1 + v2 + v3 + v4 + v5;
#pragma unroll
        for (int off = 32; off; off >>= 1) s += __shfl_xor(s, off);
        float mu = s * (1.f / C_);

        float d0 = v0 - mu, d1 = v1 - mu, d2 = v2 - mu;
        float d3 = v3 - mu, d4 = v4 - mu, d5 = v5 - mu;
        float s2 = d0*d0 + d1*d1 + d2*d2 + d3*d3 + d4*d4 + d5*d5;
#pragma unroll
        for (int off = 32; off; off >>= 1) s2 += __shfl_xor(s2, off);
        float rs = rsqrtf(s2 * (1.f / C_) + EPS_);

        float4 g4 = *(const float4*)(g + 4 * lane);
        float4 b4 = *(const float4*)(bsh + 4 * lane);
        float2 g2 = *(const float2*)(g + 256 + 2 * lane);
        float2 b2 = *(const float2*)(bsh + 256 + 2 * lane);

        float o0 = d0 * rs * g4.x + b4.x;
        float o1 = d1 * rs * g4.y + b4.y;
        float o2 = d2 * rs * g4.z + b4.z;
        float o3 = d3 * rs * g4.w + b4.w;
        float o4 = d4 * rs * g2.x + b2.x;
        float o5 = d5 * rs * g2.y + b2.y;

        u16* y = dst + (size_t)r * C_;
        uint2 w0; w0.x = pack2bf(o0, o1); w0.y = pack2bf(o2, o3);
        *(uint2*)(y + 4 * lane) = w0;
        *(u32*)(y + 256 + 2 * lane) = pack2bf(o4, o5);
    } else {
        const int KN = 384 * 384;
        int idx = (blockIdx.x - LN_BLOCKS_) * 256 + threadIdx.x;
        if (idx < KN) {
            int n = idx / 384, k = idx - n * 384;
            WvT[idx] = f2bf(Wv[k * 384 + n]);
        } else if (idx < 2 * KN) {
            int t = idx - KN;
            int n = t / 384, k = t - n * 384;
            WoutT[t] = f2bf(Wout[k * 384 + n]);
        } else if (idx < 2 * KN + WCTR_ * 384) {
            int t = idx - 2 * KN;
            int n = t / 384, k = t - n * 384;
            float v = (n < 48) ? Wo[k * 48 + n] : (n < 72 ? Wa[k * 24 + (n - 48)] : 0.f);
            WcT[t] = f2bf(v);
        } else if (idx < 2 * KN + WCTR_ * 384 + 80) {
            int n = idx - (2 * KN + WCTR_ * 384);
            bias_c[n] = (n < 48) ? bo[n] : (n < 72 ? ba[n - 48] : 0.f);
        }
    }
}

// ---------------------------------------------------------------------------
// Combined MFMA GEMM dispatch, 512 blocks x 256 threads (R1-exact, best
// measured). BK=64, depth-2 double-buffered LDS, counted vmcnt, raw
// s_barrier, XOR-swizzled LDS (both-sides: pre-swizzled global source for
// global_load_lds + same XOR on ds_read).
//   blocks 0..383:  value path, 128x128 tile: valb = fb @ WvT^T + bv (bf16)
//     XCD-affinity swizzle: m = g&127, n = g>>7.
//   blocks 384..511: small path, 128x80 tile: [offs|logits] = qb @ WcT^T + b
//     (WcT padded to 96 rows so B staging is a uniform 3 loads/thread)
// LDS: 2 x (A 128x64 + B 128x64) bf16 = 64 KB -> 2 blocks/CU.
// ---------------------------------------------------------------------------
__global__ __launch_bounds__(256) void gemm_combined(
    const u16* __restrict__ fb, const u16* __restrict__ qb,
    const u16* __restrict__ WvT, const u16* __restrict__ WcT,
    const float* __restrict__ bv, const float* __restrict__ bias_c,
    u16* __restrict__ valb, float* __restrict__ offs, float* __restrict__ logits)
{
    __shared__ __align__(16) u16 As_[2][8192];
    __shared__ __align__(16) u16 Bs_[2][8192];

    int g    = blockIdx.x;
    int tid  = threadIdx.x;
    int lane = tid & 63, wid = tid >> 6;
    int fr = lane & 15, quad = lane >> 4;

    // ds_read side swizzle: u16 col offset = (h*32 + quad*8) ^ ((row&7)*8)
    int swz  = (fr & 7) * 8;
    int off0 = (quad * 8) ^ swz;          // k-half 0; k-half 1 = off0 ^ 32

    // staging: thread covers LDS row (tid>>3)+l*32, colbytes (tid&7)*16..+15
    int srow = tid >> 3;                  // 0..31
    int csw  = ((tid & 7) ^ (srow & 7)) * 8;   // pre-swizzled global u16 col

    if (g < 384) {
        // ---------------- value path: 128x128, BK=64 ----------------
        int m0 = (g & 127) * 128, n0 = (g >> 7) * 128;   // XCD-affinity swizzle
        const u16* aSrc = fb  + (size_t)(m0 + srow) * 384 + csw;
        const u16* bSrc = WvT + (size_t)(n0 + srow) * 384 + csw;

        int wm = (wid >> 1) * 64, wn = (wid & 1) * 64;

        f32x4 zero = {0.f, 0.f, 0.f, 0.f};
        f32x4 acc[4][4];
#pragma unroll
        for (int i = 0; i < 4; ++i)
#pragma unroll
            for (int j = 0; j < 4; ++j) acc[i][j] = zero;

#define STGV(bu, t) { _Pragma("unroll") for (int l = 0; l < 4; ++l) { \
            gl_lds16(aSrc + (size_t)l * (32*384) + (t)*64, &As_[bu][tid*8 + l*2048]); \
            gl_lds16(bSrc + (size_t)l * (32*384) + (t)*64, &Bs_[bu][tid*8 + l*2048]); } }

        STGV(0, 0)
        STGV(1, 1)
#pragma unroll
        for (int t = 0; t < 6; ++t) {
            const int bu = t & 1;
            if (t < 5) vm_wait8(); else vm_wait0();   // own stage(t) landed; stage(t+1) in flight
            barrier_();                                // everyone's stage(t) landed
            bf16x8 af[4][2], bfr[4][2];
#pragma unroll
            for (int i = 0; i < 4; ++i) {
                int ra = (wm + i * 16 + fr) * 64;
                af[i][0]  = *(const bf16x8*)&As_[bu][ra + off0];
                af[i][1]  = *(const bf16x8*)&As_[bu][ra + (off0 ^ 32)];
                int rb = (wn + i * 16 + fr) * 64;
                bfr[i][0] = *(const bf16x8*)&Bs_[bu][rb + off0];
                bfr[i][1] = *(const bf16x8*)&Bs_[bu][rb + (off0 ^ 32)];
            }
            lgkm0();                                   // my frags are in regs
            barrier_();                                // everyone done reading buf bu
            if (t < 4) STGV(bu, t + 2)                 // overwrite bu; overlaps MFMAs below
#pragma unroll
            for (int i = 0; i < 4; ++i)
#pragma unroll
                for (int j = 0; j < 4; ++j) {
                    acc[i][j] = mfma16(af[i][0], bfr[j][0], acc[i][j]);
                    acc[i][j] = mfma16(af[i][1], bfr[j][1], acc[i][j]);
                }
        }
#undef STGV

#pragma unroll
        for (int i = 0; i < 4; ++i) {
            int row = m0 + wm + i * 16 + quad * 4;
#pragma unroll
            for (int j = 0; j < 4; ++j) {
                int col = n0 + wn + j * 16 + fr;
                float bcol = bv[col];
#pragma unroll
                for (int r = 0; r < 4; ++r)
                    valb[(size_t)(row + r) * C_ + col] = f2bf(acc[i][j][r] + bcol);
            }
        }
    } else {
        // ---------------- small path: 128x80 (B padded to 96), BK=64 ----------------
        int m0 = (g - 384) * 128;
        const u16* aSrc = qb  + (size_t)(m0 + srow) * 384 + csw;
        const u16* bSrc = WcT + (size_t)srow * 384 + csw;

        int wm = wid * 32;

        f32x4 zero = {0.f, 0.f, 0.f, 0.f};
        f32x4 acc[2][5];
#pragma unroll
        for (int i = 0; i < 2; ++i)
#pragma unroll
            for (int j = 0; j < 5; ++j) acc[i][j] = zero;

#define STGS(bu, t) { _Pragma("unroll") for (int l = 0; l < 4; ++l) \
            gl_lds16(aSrc + (size_t)l * (32*384) + (t)*64, &As_[bu][tid*8 + l*2048]); \
            _Pragma("unroll") for (int l = 0; l < 3; ++l) \
            gl_lds16(bSrc + (size_t)l * (32*384) + (t)*64, &Bs_[bu][tid*8 + l*2048]); }

        STGS(0, 0)
        STGS(1, 1)
#pragma unroll
        for (int t = 0; t < 6; ++t) {
            const int bu = t & 1;
            if (t < 5) vm_wait7(); else vm_wait0();
            barrier_();
            bf16x8 af[2][2], bfr[5][2];
#pragma unroll
            for (int i = 0; i < 2; ++i) {
                int ra = (wm + i * 16 + fr) * 64;
                af[i][0] = *(const bf16x8*)&As_[bu][ra + off0];
                af[i][1] = *(const bf16x8*)&As_[bu][ra + (off0 ^ 32)];
            }
#pragma unroll
            for (int j = 0; j < 5; ++j) {
                int rb = (j * 16 + fr) * 64;
                bfr[j][0] = *(const bf16x8*)&Bs_[bu][rb + off0];
                bfr[j][1] = *(const bf16x8*)&Bs_[bu][rb + (off0 ^ 32)];
            }
            lgkm0();
            barrier_();
            if (t < 4) STGS(bu, t + 2)
#pragma unroll
            for (int i = 0; i < 2; ++i)
#pragma unroll
                for (int j = 0; j < 5; ++j) {
                    acc[i][j] = mfma16(af[i][0], bfr[j][0], acc[i][j]);
                    acc[i][j] = mfma16(af[i][1], bfr[j][1], acc[i][j]);
                }
        }
#undef STGS

#pragma unroll
        for (int i = 0; i < 2; ++i) {
            int row = m0 + wm + i * 16 + quad * 4;
#pragma unroll
            for (int j = 0; j < 5; ++j) {
                int col = j * 16 + fr;
                if (col < 72) {
                    float bcol = bias_c[col];
#pragma unroll
                    for (int r = 0; r < 4; ++r) {
                        float v = acc[i][j][r] + bcol;
                        if (col < 48) offs[(size_t)(row + r) * NOFF_ + col] = v;
                        else          logits[(size_t)(row + r) * NLOG_ + (col - 48)] = v;
                    }
                }
            }
        }
    }
}

// ---------------------------------------------------------------------------
// Sampler v2: NO LDS, NO barriers, softmax+coords in registers, 16 bf16x8
// gathers per chunk, one 16B coalesced store. REGRIDDED: 1024 blocks x 384
// threads, 2 chunks/thread (virtual blocks g and g+1024). 1024 blocks =
// 4 blocks/CU <= 5-residency limit -> ONE scheduling round at 24 waves/CU
// (old 2048-block grid was 1.6 rounds + tail), plus 2-way ILP across the
// two independent chunks. Virtual blocks g, g+1024 share (g&7) -> same
// batch -> same XCD-pair L2 affinity as before. Per-chunk math identical.
// ---------------------------------------------------------------------------
__global__ __launch_bounds__(384) void sampler(
    const u16*  __restrict__ value,    // [B*LV, 384] bf16
    const float* __restrict__ rp,      // [B*LQ, 2]
    const float* __restrict__ offs,    // [B*LQ, 48]
    const float* __restrict__ logits,  // [B*LQ, 24]
    u16* __restrict__ attn)            // [B*LQ, 384] bf16
{
    int t = threadIdx.x;
    int q  = t / 48, dc = t - q * 48;
    int h  = dc >> 3;
    int col0 = dc << 3;                              // 0,8,...,376

#pragma unroll
    for (int it = 0; it < 2; ++it) {
        int g = blockIdx.x + it * 1024;              // virtual block 0..2047
        int b     = (g & 7) >> 1;                    // batch -> XCD pair
        int local = ((g >> 3) << 1) | (g & 1);       // 0..511 within batch
        int r  = b * LQ_ + local * 8 + q;

        float4 lg  = *(const float4*)(logits + (size_t)r * NLOG_ + h * 4);
        float2 rpv = *(const float2*)(rp + (size_t)r * 2);
        float4 of0 = *(const float4*)(offs + (size_t)r * NOFF_ + h * 8);
        float4 of1 = *(const float4*)(offs + (size_t)r * NOFF_ + h * 8 + 4);

        float mx = fmaxf(fmaxf(lg.x, lg.y), fmaxf(lg.z, lg.w));
        float e0 = __expf(lg.x - mx), e1 = __expf(lg.y - mx);
        float e2 = __expf(lg.z - mx), e3 = __expf(lg.w - mx);
        float rden = 1.f / (e0 + e1 + e2 + e3);
        float aws[4] = {e0 * rden, e1 * rden, e2 * rden, e3 * rden};
        float oxs[4] = {of0.x, of0.z, of1.x, of1.z};
        float oys[4] = {of0.y, of0.w, of1.y, of1.w};

        const u16* vbase = value + (size_t)b * LV_ * C_ + col0;
        float acc[8] = {0.f, 0.f, 0.f, 0.f, 0.f, 0.f, 0.f, 0.f};
#pragma unroll
        for (int p = 0; p < NP_; ++p) {
            float x = rpv.x * (float)WL_ + oxs[p] - 0.5f;
            float y = rpv.y * (float)HL_ + oys[p] - 0.5f;
            float x0f = floorf(x), y0f = floorf(y);
            float wx = x - x0f, wy = y - y0f;
            int x0 = (int)x0f, y0 = (int)y0f;
#pragma unroll
            for (int c = 0; c < 4; ++c) {
                int xi = x0 + (c & 1);
                int yi = y0 + (c >> 1);
                bool valid = (xi >= 0) && (xi < WL_) && (yi >= 0) && (yi < HL_);
                int xc = xi < 0 ? 0 : (xi > WL_ - 1 ? WL_ - 1 : xi);
                int yc = yi < 0 ? 0 : (yi > HL_ - 1 ? HL_ - 1 : yi);
                float w = ((c & 1) ? wx : 1.f - wx) * ((c >> 1) ? wy : 1.f - wy) * aws[p];
                w = valid ? w : 0.f;
                bf16x8 vv = *(const bf16x8*)(vbase + (size_t)(yc * WL_ + xc) * C_);
#pragma unroll
                for (int e = 0; e < 8; ++e) acc[e] += w * (float)vv[e];
            }
        }

        uint4 o;
        o.x = pack2bf(acc[0], acc[1]);
        o.y = pack2bf(acc[2], acc[3]);
        o.z = pack2bf(acc[4], acc[5]);
        o.w = pack2bf(acc[6], acc[7]);
        *(uint4*)(attn + (size_t)r * C_ + col0) = o;
    }
}

// ---------------------------------------------------------------------------
// Out GEMM: out = query + gamma * (attn @ WoutT^T + bout). 128x96 tile ->
// 512 blocks = exactly 2 blocks/CU (R1-exact). BK=64, depth-2 dbuf, counted
// vmcnt, swizzled LDS. Waves 2x2, wave tile 64x48, acc[4][3].
// XCD-affinity: m = g&127, n = g>>7 (same-m blocks share an XCD for attn L2).
// ---------------------------------------------------------------------------
__global__ __launch_bounds__(256) void out_gemm(
    const u16* __restrict__ A, const u16* __restrict__ Bt,
    const float* __restrict__ bout, const float* __restrict__ gamma,
    const float* __restrict__ query, float* __restrict__ out)
{
    __shared__ __align__(16) u16 As_[2][8192];
    __shared__ __align__(16) u16 Bs_[2][8192];

    int g    = blockIdx.x;
    int tid  = threadIdx.x;
    int lane = tid & 63, wid = tid >> 6;
    int fr = lane & 15, quad = lane >> 4;

    int swz  = (fr & 7) * 8;
    int off0 = (quad * 8) ^ swz;
    int srow = tid >> 3;
    int csw  = ((tid & 7) ^ (srow & 7)) * 8;

    int m0 = (g & 127) * 128, n0 = (g >> 7) * 96;
    const u16* aSrc = A  + (size_t)(m0 + srow) * 384 + csw;
    const u16* bSrc = Bt + (size_t)(n0 + srow) * 384 + csw;

    int wm = (wid >> 1) * 64, wn = (wid & 1) * 48;

    f32x4 zero = {0.f, 0.f, 0.f, 0.f};
    f32x4 acc[4][3];
#pragma unroll
    for (int i = 0; i < 4; ++i)
#pragma unroll
        for (int j = 0; j < 3; ++j) acc[i][j] = zero;

#define STGO(bu, t) { _Pragma("unroll") for (int l = 0; l < 4; ++l) \
        gl_lds16(aSrc + (size_t)l * (32*384) + (t)*64, &As_[bu][tid*8 + l*2048]); \
        _Pragma("unroll") for (int l = 0; l < 3; ++l) \
        gl_lds16(bSrc + (size_t)l * (32*384) + (t)*64, &Bs_[bu][tid*8 + l*2048]); }

    STGO(0, 0)
    STGO(1, 1)
#pragma unroll
    for (int t = 0; t < 6; ++t) {
        const int bu = t & 1;
        if (t < 5) vm_wait7(); else vm_wait0();
        barrier_();
        bf16x8 af[4][2], bfr[3][2];
#pragma unroll
        for (int i = 0; i < 4; ++i) {
            int ra = (wm + i * 16 + fr) * 64;
            af[i][0] = *(const bf16x8*)&As_[bu][ra + off0];
            af[i][1] = *(const bf16x8*)&As_[bu][ra + (off0 ^ 32)];
        }
#pragma unroll
        for (int j = 0; j < 3; ++j) {
            int rb = (wn + j * 16 + fr) * 64;
            bfr[j][0] = *(const bf16x8*)&Bs_[bu][rb + off0];
            bfr[j][1] = *(const bf16x8*)&Bs_[bu][rb + (off0 ^ 32)];
        }
        lgkm0();
        barrier_();
        if (t < 4) STGO(bu, t + 2)
#pragma unroll
        for (int i = 0; i < 4; ++i)
#pragma unroll
            for (int j = 0; j < 3; ++j) {
                acc[i][j] = mfma16(af[i][0], bfr[j][0], acc[i][j]);
                acc[i][j] = mfma16(af[i][1], bfr[j][1], acc[i][j]);
            }
    }
#undef STGO

#pragma unroll
    for (int i = 0; i < 4; ++i) {
        int row = m0 + wm + i * 16 + quad * 4;
#pragma unroll
        for (int j = 0; j < 3; ++j) {
            int col = n0 + wn + j * 16 + fr;
            float bc = bout[col], gm = gamma[col];
#pragma unroll
            for (int r = 0; r < 4; ++r) {
                size_t o = (size_t)(row + r) * C_ + col;
                out[o] = query[o] + gm * (acc[i][j][r] + bc);
            }
        }
    }
}

// ---------------------------------------------------------------------------
extern "C" void kernel_launch(void* const* d_in, const int* in_sizes, int n_in,
                              void* d_out, int out_size, void* d_ws, size_t ws_size,
                              hipStream_t stream)
{
    const float* query  = (const float*)d_in[0];
    const float* rp     = (const float*)d_in[1];
    const float* feat   = (const float*)d_in[2];
    const float* gamma  = (const float*)d_in[9];
    const float* Wv     = (const float*)d_in[10];
    const float* bv     = (const float*)d_in[11];
    const float* Wo     = (const float*)d_in[12];
    const float* bo     = (const float*)d_in[13];
    const float* Wa     = (const float*)d_in[14];
    const float* ba     = (const float*)d_in[15];
    const float* Wout   = (const float*)d_in[16];
    const float* bout   = (const float*)d_in[17];
    float* out = (float*)d_out;

    // Workspace layout
    u16* wsu    = (u16*)d_ws;
    u16* qb     = wsu;                                   // 16384*384
    u16* fb     = qb    + (size_t)ROWS_ * C_;
    u16* valb   = fb    + (size_t)ROWS_ * C_;
    u16* attnb  = valb  + (size_t)ROWS_ * C_;
    u16* WvT    = attnb + (size_t)ROWS_ * C_;            // 384*384
    u16* WoutT  = WvT   + 384 * 384;
    u16* WcT    = WoutT + 384 * 384;                     // 96*384 (80 used)
    float* offs   = (float*)(WcT + WCTR_ * 384);         // 16384*48
    float* logits = offs + (size_t)ROWS_ * NOFF_;        // 16384*24
    float* bias_c = logits + (size_t)ROWS_ * NLOG_;      // 80

    // 1) LayerNorm (q,f -> bf16, vectorized) + weight transpose/convert
    ln_prep<<<LN_BLOCKS_ + PREP_BLOCKS_, 256, 0, stream>>>(
        query, feat,
        (const float*)d_in[5], (const float*)d_in[6],
        (const float*)d_in[7], (const float*)d_in[8],
        qb, fb, Wv, Wout, Wo, Wa, bo, ba, WvT, WoutT, WcT, bias_c);

    // 2) value GEMM 128x128 (384 blocks, XCD-affinity) + offs/logits GEMM
    //    (R1-exact: BK=64, depth-2 dbuf, counted vmcnt, swizzled LDS)
    gemm_combined<<<512, 256, 0, stream>>>(fb, qb, WvT, WcT, bv, bias_c,
                                           valb, offs, logits);

    // 3) sampler v2: 1024 blocks x 384 thr, 2 chunks/thread, single round
    sampler<<<1024, 384, 0, stream>>>(valb, rp, offs, logits, attnb);

    // 4) out = query + gamma * (attn @ Wout + bout), 128x96 x 512 blocks
    out_gemm<<<512, 256, 0, stream>>>(attnb, WoutT, bout, gamma, query, out);
}